// Round 2
// baseline (1681.580 us; speedup 1.0000x reference)
//
#include <hip/hip_runtime.h>
#include <hip/hip_bf16.h>
#include <cstdint>

// DecoderRNN: LSTM(31 steps, B=128, E=512, H=1024) + FC to V=32000.
// bf16 MFMA everywhere (fp32 accum), fp32 cell state.
//   1) prep: bf16 weight conversion, embedding gather, bias sum, zero out[:,0,:]
//   2) Gx = X @ W_ih^T + (b_ih+b_hh)      [3968x4096x512]
//   3) 31x fused { gates = h @ W_hh^T + Gx[t]; cell-update } in ONE kernel:
//      per-wave tile = 32 rows x (4 gates x 16 cols) so all 4 gate values for
//      (m,j) sit in the same lane/register slot -> in-register cell update.
//   4) out[:,1:,:] = Hseq @ fc_W^T + fc_b [3968x32000x1024, row-scatter]

typedef unsigned short u16;
typedef __attribute__((ext_vector_type(8))) short bf16x8;
typedef __attribute__((ext_vector_type(4))) float f32x4;

static constexpr int B_ = 128, T_ = 32, E_ = 512, H_ = 1024, V_ = 32000;
static constexpr int TS = T_ - 1;          // 31 time steps
static constexpr int M_SEQ = TS * B_;      // 3968
static constexpr int G4 = 4 * H_;          // 4096

__device__ __forceinline__ u16 f2bf(float x) {
  union { __hip_bfloat16 b; u16 u; } c; c.b = __float2bfloat16(x); return c.u;
}

__device__ __forceinline__ void gload_lds16(const void* g, void* l) {
  __builtin_amdgcn_global_load_lds(
      (const __attribute__((address_space(1))) unsigned int*)g,
      (__attribute__((address_space(3))) unsigned int*)l, 16, 0, 0);
}

__device__ __forceinline__ float sigm(float x) { return 1.f / (1.f + expf(-x)); }

// ---------------- prep kernels ----------------

__global__ void cvt_bf16x4(const float* __restrict__ s, u16* __restrict__ d, int n) {
  int i = (blockIdx.x * blockDim.x + threadIdx.x) * 4;
  if (i >= n) return;
  const float4 v = *(const float4*)(s + i);
  *(ushort4*)(d + i) = make_ushort4(f2bf(v.x), f2bf(v.y), f2bf(v.z), f2bf(v.w));
}

__global__ void addb(const float* __restrict__ a, const float* __restrict__ b,
                     float* __restrict__ o) {
  int i = blockIdx.x * blockDim.x + threadIdx.x;
  if (i < G4) o[i] = a[i] + b[i];
}

__global__ void gather_x(const int* __restrict__ cap, const float* __restrict__ emb,
                         u16* __restrict__ X) {
  int i4 = blockIdx.x * blockDim.x + threadIdx.x;   // over 3968*512/4
  if (i4 >= M_SEQ * (E_ / 4)) return;
  int i = i4 * 4;
  int tb = i >> 9;         // row in X: t*128 + b
  int e = i & (E_ - 1);
  int t = tb >> 7;
  int b = tb & 127;
  int row = cap[b * T_ + t];
  const float4 v = *(const float4*)(emb + (long)row * E_ + e);
  *(ushort4*)(X + i) = make_ushort4(f2bf(v.x), f2bf(v.y), f2bf(v.z), f2bf(v.w));
}

__global__ void hc_init(const float* __restrict__ f, u16* __restrict__ h,
                        float* __restrict__ c) {
  int i = blockIdx.x * blockDim.x + threadIdx.x;
  if (i < B_ * H_) { float v = f[i]; h[i] = f2bf(v); c[i] = v; }
}

__global__ void zero_t0(float* __restrict__ out) {
  int i4 = blockIdx.x * blockDim.x + threadIdx.x;   // over 128*32000/4
  if (i4 >= B_ * (V_ / 4)) return;
  int b = i4 / (V_ / 4), v4 = i4 % (V_ / 4);
  *(float4*)(out + (long)b * T_ * V_ + v4 * 4) = make_float4(0.f, 0.f, 0.f, 0.f);
}

// ---------------- GEMM: C[M,N] = A[M,K] @ B[N,K]^T + bias[n] ----------------
// m97 structure: 128x128 tile, 4 waves 2x2 each 64x64, 16x16x32 bf16 MFMA,
// global_load_lds width-16 staging, 2-barrier K loop.
// SCATTER=1 remaps row m=(t*128+b) -> out row (b*32 + t + 1)  (fc projection).

template<int SCATTER>
__global__ __launch_bounds__(256)
void gemm_bt(const u16* __restrict__ A, int lda,
             const u16* __restrict__ B, int ldb,
             float* __restrict__ C, long ldc,
             const float* __restrict__ bias,
             int K, int ntn)
{
  constexpr int BM = 128, BN = 128, NFR = 4;
  const int bid = blockIdx.x;
  const int mt = bid / ntn, nt = bid % ntn;
  const int tid = threadIdx.x;
  const int wid = tid >> 6, lane = tid & 63;
  const int wm = (wid >> 1) * 64, wn = (wid & 1) * 64;
  const int l15 = lane & 15, l4 = lane >> 4;

  __shared__ __align__(16) u16 As[BM * 32];
  __shared__ __align__(16) u16 Bs[BN * 32];

  f32x4 acc[4][NFR] = {};

  const u16* Ag = A + (long)(mt * BM + (tid >> 2)) * lda + (tid & 3) * 8;
  const u16* Bg = B + (long)(nt * BN + (tid >> 2)) * ldb + (tid & 3) * 8;
  char* AsW = (char*)As + wid * 1024;
  char* BsW = (char*)Bs + wid * 1024;

  for (int kt = 0; kt < K; kt += 32) {
    gload_lds16(Ag + kt, AsW);
    gload_lds16(Ag + 64 * (long)lda + kt, AsW + 4096);
    gload_lds16(Bg + kt, BsW);
    gload_lds16(Bg + 64 * (long)ldb + kt, BsW + 4096);
    __syncthreads();   // compiler drains vmcnt before barrier

    const u16* Ab = As + (wm + l15) * 32 + l4 * 8;
    const u16* Bb = Bs + (wn + l15) * 32 + l4 * 8;
    bf16x8 af[4], bfr[NFR];
#pragma unroll
    for (int i = 0; i < 4; ++i) af[i] = *(const bf16x8*)(Ab + i * 16 * 32);
#pragma unroll
    for (int j = 0; j < NFR; ++j) bfr[j] = *(const bf16x8*)(Bb + j * 16 * 32);
#pragma unroll
    for (int i = 0; i < 4; ++i)
#pragma unroll
      for (int j = 0; j < NFR; ++j)
        acc[i][j] = __builtin_amdgcn_mfma_f32_16x16x32_bf16(af[i], bfr[j], acc[i][j], 0, 0, 0);
    __syncthreads();
  }

  // C/D layout: col = lane&15, row = (lane>>4)*4 + r  (m89/m91 verified)
  const int grow0 = mt * BM + wm + l4 * 4;
  const int gcol0 = nt * BN + wn + l15;
#pragma unroll
  for (int i = 0; i < 4; ++i) {
#pragma unroll
    for (int j = 0; j < NFR; ++j) {
      const int col = gcol0 + j * 16;
      const float bv = bias ? bias[col] : 0.0f;
#pragma unroll
      for (int r = 0; r < 4; ++r) {
        const int row = grow0 + i * 16 + r;
        float v = acc[i][j][r] + bv;
        long o;
        if constexpr (SCATTER) {
          const int t = row >> 7, b = row & 127;
          o = ((long)(b * T_ + t + 1)) * ldc + col;
        } else {
          o = (long)row * ldc + col;
        }
        C[o] = v;
      }
    }
  }
}

// ---------------- fused LSTM step: gates GEMM + cell update ----------------
// grid = 64 blocks, block owns h-cols j0..j0+15 (all 4 gates for them).
// 4 waves partition the 128 rows (32 rows each); per wave: 2 M-frags x 4
// gate-frags. Gate g's pre-activation for (m,j) is acc[mi][g][r] -- same
// lane, same r for all g -> in-register cell update, no exchange.

__global__ __launch_bounds__(256)
void lstm_step(const u16* __restrict__ h_in,    // 128 x 1024 bf16
               const u16* __restrict__ Whh,     // 4096 x 1024 bf16
               const float* __restrict__ gx,    // 128 x 4096 fp32 (this step)
               float* __restrict__ c,           // 128 x 1024 fp32 in/out
               u16* __restrict__ h_out,         // 128 x 1024 bf16 (ping-pong)
               u16* __restrict__ hseq)          // this step's Hseq slice
{
  const int tid = threadIdx.x;
  const int wid = tid >> 6, lane = tid & 63;
  const int l15 = lane & 15, l4 = lane >> 4;
  const int j0 = blockIdx.x * 16;

  __shared__ __align__(16) u16 As[128 * 32];   // h tile   (8 KB)
  __shared__ __align__(16) u16 Bs[64 * 32];    // 4 gates x 16 Whh rows (4 KB)

  f32x4 acc[2][4] = {};

  const u16* Ag = h_in + (long)(tid >> 2) * H_ + (tid & 3) * 8;
  const int vr = tid >> 2;                     // 0..63: gate = vr>>4, row-in-slab = vr&15
  const u16* Bg = Whh + (long)((vr >> 4) * H_ + j0 + (vr & 15)) * H_ + (tid & 3) * 8;
  char* AsW = (char*)As + wid * 1024;
  char* BsW = (char*)Bs + wid * 1024;

  for (int kt = 0; kt < H_; kt += 32) {
    gload_lds16(Ag + kt, AsW);
    gload_lds16(Ag + 64 * H_ + kt, AsW + 4096);
    gload_lds16(Bg + kt, BsW);
    __syncthreads();

    const u16* Ab = As + (wid * 32 + l15) * 32 + l4 * 8;
    const u16* Bb = Bs + l15 * 32 + l4 * 8;
    bf16x8 af[2], bfr[4];
#pragma unroll
    for (int i = 0; i < 2; ++i) af[i] = *(const bf16x8*)(Ab + i * 16 * 32);
#pragma unroll
    for (int g = 0; g < 4; ++g) bfr[g] = *(const bf16x8*)(Bb + g * 16 * 32);
#pragma unroll
    for (int i = 0; i < 2; ++i)
#pragma unroll
      for (int g = 0; g < 4; ++g)
        acc[i][g] = __builtin_amdgcn_mfma_f32_16x16x32_bf16(af[i], bfr[g], acc[i][g], 0, 0, 0);
    __syncthreads();
  }

  const int j = j0 + l15;
#pragma unroll
  for (int mi = 0; mi < 2; ++mi) {
#pragma unroll
    for (int r = 0; r < 4; ++r) {
      const int m = wid * 32 + mi * 16 + l4 * 4 + r;
      const float* gr = gx + (long)m * G4 + j;
      float gi = sigm(acc[mi][0][r] + gr[0]);
      float gf = sigm(acc[mi][1][r] + gr[H_]);
      float gg = tanhf(acc[mi][2][r] + gr[2 * H_]);
      float go = sigm(acc[mi][3][r] + gr[3 * H_]);
      const int idx = m * H_ + j;
      float cn = gf * c[idx] + gi * gg;
      c[idx] = cn;
      u16 hb = f2bf(go * tanhf(cn));
      h_out[idx] = hb;
      hseq[idx] = hb;
    }
  }
}

// ---------------- launch ----------------

extern "C" void kernel_launch(void* const* d_in, const int* in_sizes, int n_in,
                              void* d_out, int out_size, void* d_ws, size_t ws_size,
                              hipStream_t stream) {
  const float* features = (const float*)d_in[0];
  const int*   captions = (const int*)d_in[1];
  const float* embed    = (const float*)d_in[2];
  const float* W_ih     = (const float*)d_in[3];
  const float* W_hh     = (const float*)d_in[4];
  const float* b_ih     = (const float*)d_in[5];
  const float* b_hh     = (const float*)d_in[6];
  const float* fc_W     = (const float*)d_in[7];
  const float* fc_b     = (const float*)d_in[8];
  float* out = (float*)d_out;

  size_t off = 0;
  auto alloc = [&](size_t bytes) {
    void* p = (char*)d_ws + off;
    off += (bytes + 255) & ~(size_t)255;
    return p;
  };
  u16*  Wih_b = (u16*)alloc((size_t)G4 * E_ * 2);
  u16*  Whh_b = (u16*)alloc((size_t)G4 * H_ * 2);
  u16*  fcW_b = (u16*)alloc((size_t)V_ * H_ * 2);
  u16*  Xb    = (u16*)alloc((size_t)M_SEQ * E_ * 2);
  u16*  Hseq  = (u16*)alloc((size_t)M_SEQ * H_ * 2);
  u16*  hb0   = (u16*)alloc((size_t)B_ * H_ * 2);
  u16*  hb1   = (u16*)alloc((size_t)B_ * H_ * 2);
  float* cst  = (float*)alloc((size_t)B_ * H_ * 4);
  float* Gx   = (float*)alloc((size_t)M_SEQ * G4 * 4);
  float* bsum = (float*)alloc((size_t)G4 * 4);
  if (off > ws_size) return;   // workspace too small -> fail validation loudly

  // prep
  cvt_bf16x4<<<(G4 * E_ / 4 + 255) / 256, 256, 0, stream>>>(W_ih, Wih_b, G4 * E_);
  cvt_bf16x4<<<(G4 * H_ / 4 + 255) / 256, 256, 0, stream>>>(W_hh, Whh_b, G4 * H_);
  cvt_bf16x4<<<(V_ * H_ / 4 + 255) / 256, 256, 0, stream>>>(fc_W, fcW_b, V_ * H_);
  addb<<<(G4 + 255) / 256, 256, 0, stream>>>(b_ih, b_hh, bsum);
  gather_x<<<(M_SEQ * E_ / 4 + 255) / 256, 256, 0, stream>>>(captions, embed, Xb);
  hc_init<<<(B_ * H_ + 255) / 256, 256, 0, stream>>>(features, hb0, cst);
  zero_t0<<<(B_ * V_ / 4 + 255) / 256, 256, 0, stream>>>(out);

  // Gx = X @ W_ih^T + bsum   (M=3968, N=4096, K=512)
  gemm_bt<0><<<(M_SEQ / 128) * (G4 / 128), 256, 0, stream>>>(
      Xb, E_, Wih_b, E_, Gx, G4, bsum, E_, G4 / 128);

  // serial LSTM: 31 fused steps (ping-pong h)
  u16* hp[2] = { hb0, hb1 };
  for (int t = 0; t < TS; ++t) {
    lstm_step<<<H_ / 16, 256, 0, stream>>>(
        hp[t & 1], Whh_b, Gx + (size_t)t * B_ * G4, cst, hp[(t + 1) & 1],
        Hseq + (size_t)t * B_ * H_);
  }

  // out[:,1:,:] = Hseq @ fc_W^T + fc_b   (M=3968, N=32000, K=1024)
  gemm_bt<1><<<(M_SEQ / 128) * (V_ / 128), 256, 0, stream>>>(
      Hseq, H_, fcW_b, H_, out, V_, fc_b, H_, V_ / 128);
}